// Round 12
// baseline (51.876 us; speedup 1.0000x reference)
//
#include <hip/hip_runtime.h>
#include <hip/hip_fp16.h>
#include <math.h>

// (B,Tq,Tk,U) = (32,1024,1024,256), f32 in/out.
#define NB 32
#define TQ 1024
#define TK 1024
#define UD 256

typedef __attribute__((ext_vector_type(8))) _Float16 f16x8;
typedef __attribute__((ext_vector_type(4))) float f32x4;

__device__ __forceinline__ float fast_tanh(float x) {
  const float e = __expf(2.0f * x);
  return 1.0f - 2.0f / (e + 1.0f);
}

// Direct global->LDS, 16 B/lane, LDS dest = wave-uniform base + lane*16.
__device__ __forceinline__ void gload_lds16(const void* g, void* l) {
  __builtin_amdgcn_global_load_lds(
      (const __attribute__((address_space(1))) void*)g,
      (__attribute__((address_space(3))) void*)l, 16, 0, 0);
}

// ---------------------------------------------------------------------------
// K0: Wq f32 -> f16, k-slot-major: wq16t[ks][u][8] (ks = k>>3).
// ---------------------------------------------------------------------------
__global__ __launch_bounds__(256) void cvt_wq_kernel(
    const float* __restrict__ Wq, _Float16* __restrict__ wq16t) {
  const int idx = blockIdx.x * 256 + threadIdx.x;  // 8192
  const int u = idx >> 5;
  const int ks = idx & 31;
  const float4 w0 = *reinterpret_cast<const float4*>(Wq + u * UD + ks * 8);
  const float4 w1 = *reinterpret_cast<const float4*>(Wq + u * UD + ks * 8 + 4);
  f16x8 h;
  h[0] = (_Float16)w0.x; h[1] = (_Float16)w0.y;
  h[2] = (_Float16)w0.z; h[3] = (_Float16)w0.w;
  h[4] = (_Float16)w1.x; h[5] = (_Float16)w1.y;
  h[6] = (_Float16)w1.z; h[7] = (_Float16)w1.w;
  *reinterpret_cast<f16x8*>(wq16t + ((size_t)ks * 256 + u) * 8) = h;
}

// ---------------------------------------------------------------------------
// K1: sk[r] = sum_u v[u] * tanh( sum_c key[r,c] * Wq[u,c] )   (MFMA f16)
// 1024 blocks x 512 thr (8 waves: wr=row-half x wc=u-quarter). 32 rows/block.
// A: key f32, k-slot-major [ks 0..31][slot 0..63 of 16B], slot XOR-swizzled
//    by (ks&7); ALL 32 KB issued via global_load_lds up front (bulk MLP),
//    per-lane source pre-swizzled so LDS stays HW-linear.
// B: wq16t f16 [4 ks][256 u][8], 16 KB/phase, double-buffered gload_lds.
// LDS = 64 KB -> 2 blocks/CU (16 waves/CU). VGPR ~50.
// ---------------------------------------------------------------------------
__global__ __launch_bounds__(512) void sk_mfma_kernel(
    const float* __restrict__ key, const _Float16* __restrict__ wq16t,
    const float* __restrict__ v, float* __restrict__ sk) {
  __shared__ __align__(16) float At[8192];          // 32 KB
  __shared__ __align__(16) _Float16 Bt[2][8192];    // 2 x 16 KB

  const int tid = threadIdx.x;
  const int lane = tid & 63;
  const int wid = tid >> 6;  // 0..7 (uniform per wave)
  const int wr = wid >> 2;   // 0..1: row half
  const int wc = wid & 3;    // 0..3: u quarter
  const int lx = lane & 15;
  const int lg = lane >> 4;
  const int row0 = blockIdx.x * 32;

  // ---- issue ALL of A: 4 gload_lds/thread; (i,wid) <-> ks plane ----
#pragma unroll
  for (int i = 0; i < 4; ++i) {
    const int ks = i * 8 + wid;                  // wave-uniform
    const int slot_log = lane ^ (ks & 7);        // pre-swizzled source
    const int r = slot_log >> 1;
    const int h = slot_log & 1;
    gload_lds16(key + (size_t)(row0 + r) * UD + ks * 8 + h * 4,
                (char*)At + ks * 1024);
  }
  // ---- issue B phase 0 (linear copy of wq16t[0..3][*][*]) ----
#pragma unroll
  for (int i = 0; i < 2; ++i) {
    const int Sw = i * 512 + wid * 64;           // wave-uniform window
    gload_lds16(wq16t + (size_t)(Sw + lane) * 8, (char*)Bt[0] + Sw * 16);
  }
  __syncthreads();  // drains the bulk A stream + B0

  f32x4 acc[4];
#pragma unroll
  for (int n = 0; n < 4; ++n) acc[n] = (f32x4){0.f, 0.f, 0.f, 0.f};

#pragma unroll
  for (int p = 0; p < 8; ++p) {
    const int cur = p & 1;
    if (p < 7) {  // async-issue next B tile into the freed buffer
#pragma unroll
      for (int i = 0; i < 2; ++i) {
        const int Sw = i * 512 + wid * 64;
        gload_lds16(wq16t + (size_t)(p + 1) * 8192 + (size_t)(Sw + lane) * 8,
                    (char*)Bt[cur ^ 1] + Sw * 16);
      }
    }
    const int ksg = p * 4 + lg;
    // A fragment: two swizzled 16B slots, cvt f32->f16
    const int row = wr * 16 + lx;
    const float* ap0 =
        At + ksg * 256 + ((row * 2) ^ (ksg & 7)) * 4;
    const float* ap1 =
        At + ksg * 256 + ((row * 2 + 1) ^ (ksg & 7)) * 4;
    const f32x4 alo = *reinterpret_cast<const f32x4*>(ap0);
    const f32x4 ahi = *reinterpret_cast<const f32x4*>(ap1);
    f16x8 af;
    af[0] = (_Float16)alo[0]; af[1] = (_Float16)alo[1];
    af[2] = (_Float16)alo[2]; af[3] = (_Float16)alo[3];
    af[4] = (_Float16)ahi[0]; af[5] = (_Float16)ahi[1];
    af[6] = (_Float16)ahi[2]; af[7] = (_Float16)ahi[3];
    f16x8 bf[4];
#pragma unroll
    for (int n = 0; n < 4; ++n)
      bf[n] = *reinterpret_cast<const f16x8*>(
          Bt[cur] + ((size_t)(lg * 256 + wc * 64 + n * 16 + lx)) * 8);
#pragma unroll
    for (int n = 0; n < 4; ++n)
      acc[n] = __builtin_amdgcn_mfma_f32_16x16x32_f16(af, bf[n], acc[n], 0, 0, 0);
    __syncthreads();
  }

  // ---- epilogue: tanh, dot v, shfl-reduce over lx, LDS-reduce over wc ----
  // acc[n] reg r: row_local = wr*16 + lg*4 + r ; u = wc*64 + n*16 + lx
  float vv[4];
#pragma unroll
  for (int n = 0; n < 4; ++n) vv[n] = v[wc * 64 + n * 16 + lx];

  float* red = (float*)At;  // At free after final barrier
  float part[4] = {0.f, 0.f, 0.f, 0.f};
#pragma unroll
  for (int n = 0; n < 4; ++n)
#pragma unroll
    for (int r = 0; r < 4; ++r) part[r] += vv[n] * fast_tanh(acc[n][r]);

#pragma unroll
  for (int r = 0; r < 4; ++r) {
    float s = part[r];
    s += __shfl_xor(s, 1);
    s += __shfl_xor(s, 2);
    s += __shfl_xor(s, 4);
    s += __shfl_xor(s, 8);
    if (lx == 0) red[(wr * 16 + lg * 4 + r) * 4 + wc] = s;
  }
  __syncthreads();
  if (tid < 32) {
    sk[row0 + tid] = red[tid * 4 + 0] + red[tid * 4 + 1] + red[tid * 4 + 2] +
                     red[tid * 4 + 3];
  }
}

// ---------------------------------------------------------------------------
// K2: fused softmax + PV partial (contiguous 1 KB rows; streams at 4.3 TB/s).
// ---------------------------------------------------------------------------
__global__ __launch_bounds__(256) void pv_kernel(
    const float* __restrict__ sk, const int* __restrict__ vlen,
    const float* __restrict__ value, float* __restrict__ part) {
  const int b = blockIdx.x >> 4;
  const int ch = blockIdx.x & 15;
  const int tid = threadIdx.x;
  const int vl = vlen[b];
  __shared__ float wbuf[64];
  __shared__ float red4[8];
  const float* skb = sk + b * TK;

  if (vl == 0) {  // uniform softmax over the constant-fill row
    if (tid < 64) wbuf[tid] = 1.0f / (float)TK;
  } else {
    float m = -1e30f;
#pragma unroll
    for (int idx = 0; idx < 4; ++idx) {
      const int k = tid + idx * 256;
      if (k < vl) m = fmaxf(m, skb[k]);
    }
    for (int off = 1; off < 64; off <<= 1) m = fmaxf(m, __shfl_xor(m, off));
    if ((tid & 63) == 0) red4[tid >> 6] = m;
    __syncthreads();
    m = fmaxf(fmaxf(red4[0], red4[1]), fmaxf(red4[2], red4[3]));
    float zs = 0.f;
#pragma unroll
    for (int idx = 0; idx < 4; ++idx) {
      const int k = tid + idx * 256;
      zs += (k < vl) ? __expf(skb[k] - m) : 0.f;
    }
    for (int off = 1; off < 64; off <<= 1) zs += __shfl_xor(zs, off);
    if ((tid & 63) == 0) red4[4 + (tid >> 6)] = zs;
    __syncthreads();
    const float rz = 1.0f / (red4[4] + red4[5] + red4[6] + red4[7]);
    if (tid < 64) {
      const int k = ch * 64 + tid;
      wbuf[tid] = (k < vl) ? __expf(skb[k] - m) * rz : 0.f;
    }
  }
  __syncthreads();

  const int d = tid;
  const float* vb = value + ((size_t)b * TK + ch * 64) * UD;
  float acc = 0.f;
#pragma unroll 8
  for (int k = 0; k < 64; ++k)
    acc = fmaf(wbuf[k], vb[(size_t)k * UD + d], acc);
  part[(size_t)(b * 16 + ch) * UD + d] = acc;
}

// ---------------------------------------------------------------------------
// K3: reduce 16 partials -> out_row, broadcast over 64 q rows/block.
// ---------------------------------------------------------------------------
__global__ __launch_bounds__(256) void bcast_kernel(
    const float* __restrict__ part, float* __restrict__ out) {
  const int b = blockIdx.x >> 4;
  const int qc = blockIdx.x & 15;
  const int tid = threadIdx.x;
  const int qoff = tid >> 6;      // 0..3
  const int dd = (tid & 63) * 4;  // 0..252

  float4 s = make_float4(0.f, 0.f, 0.f, 0.f);
#pragma unroll
  for (int c = 0; c < 16; ++c) {
    const float4 p = *reinterpret_cast<const float4*>(
        &part[(size_t)(b * 16 + c) * UD + dd]);
    s.x += p.x; s.y += p.y; s.z += p.z; s.w += p.w;
  }

  float* ob = out + (size_t)b * TQ * UD + (size_t)qc * 64 * UD;
#pragma unroll 4
  for (int q4 = 0; q4 < 16; ++q4) {
    *reinterpret_cast<float4*>(&ob[(size_t)(q4 * 4 + qoff) * UD + dd]) = s;
  }
}

// ---------------------------------------------------------------------------
extern "C" void kernel_launch(void* const* d_in, const int* in_sizes, int n_in,
                              void* d_out, int out_size, void* d_ws,
                              size_t ws_size, hipStream_t stream) {
  // inputs: 0 query, 1 key, 2 value, 3 valid_length, 4 W_k, 5 W_q, 6 v
  const float* key = (const float*)d_in[1];
  const float* value = (const float*)d_in[2];
  const int* vlen = (const int*)d_in[3];
  const float* Wq = (const float*)d_in[5];
  const float* v = (const float*)d_in[6];
  float* out = (float*)d_out;

  char* ws = (char*)d_ws;
  _Float16* wq16t = (_Float16*)(ws);    // 128 KB (k-slot-major f16 Wq)
  float* sk = (float*)(ws + 131072);    // 128 KB
  float* part = (float*)(ws + 262144);  // 512 KB

  cvt_wq_kernel<<<32, 256, 0, stream>>>(Wq, wq16t);
  sk_mfma_kernel<<<(NB * TK) / 32, 512, 0, stream>>>(key, wq16t, v, sk);
  pv_kernel<<<NB * 16, 256, 0, stream>>>(sk, vlen, value, part);
  bcast_kernel<<<NB * 16, 256, 0, stream>>>(part, out);
}

// Round 13
// 44.913 us; speedup vs baseline: 1.1550x; 1.1550x over previous
//
#include <hip/hip_runtime.h>
#include <hip/hip_fp16.h>
#include <math.h>

// (B,Tq,Tk,U) = (32,1024,1024,256), f32 in/out.
#define NB 32
#define TQ 1024
#define TK 1024
#define UD 256

typedef __attribute__((ext_vector_type(8))) _Float16 f16x8;
typedef __attribute__((ext_vector_type(4))) _Float16 f16x4;
typedef __attribute__((ext_vector_type(4))) float f32x4;

__device__ __forceinline__ float fast_tanh(float x) {
  const float e = __expf(2.0f * x);
  return 1.0f - 2.0f / (e + 1.0f);
}

// ---------------------------------------------------------------------------
// K0: Wq f32 -> f16, k-slot-major: wq16t[ks][u][8] (ks = k>>3).
// ---------------------------------------------------------------------------
__global__ __launch_bounds__(256) void cvt_wq_kernel(
    const float* __restrict__ Wq, _Float16* __restrict__ wq16t) {
  const int idx = blockIdx.x * 256 + threadIdx.x;  // 8192
  const int u = idx >> 5;
  const int ks = idx & 31;
  const float4 w0 = *reinterpret_cast<const float4*>(Wq + u * UD + ks * 8);
  const float4 w1 = *reinterpret_cast<const float4*>(Wq + u * UD + ks * 8 + 4);
  f16x8 h;
  h[0] = (_Float16)w0.x; h[1] = (_Float16)w0.y;
  h[2] = (_Float16)w0.z; h[3] = (_Float16)w0.w;
  h[4] = (_Float16)w1.x; h[5] = (_Float16)w1.y;
  h[6] = (_Float16)w1.z; h[7] = (_Float16)w1.w;
  *reinterpret_cast<f16x8*>(wq16t + ((size_t)ks * 256 + u) * 8) = h;
}

// ---------------------------------------------------------------------------
// K1 (FUSED): block (b,ch) = 64 rows of one batch.
//  Phase 1 (MLP, MFMA f16, r11 structure): sval[r] = sum_u v[u]*tanh(...)
//  Phase 2: e[r] = vl==0 ? 1 : (k<vl ? exp(sval[r]) : 0)   [UNNORMALIZED]
//           zpart[b,ch] = sum_r e[r]
//  Phase 3: part[b,ch,d] = sum_r e[r]*value[b,ch*64+r,d]   (contiguous reads)
// No cross-block dependencies: all key+value reads issue in ONE kernel.
// ---------------------------------------------------------------------------
__global__ __launch_bounds__(512, 4) void fused_kernel(
    const float* __restrict__ key, const _Float16* __restrict__ wq16t,
    const float* __restrict__ v, const int* __restrict__ vlen,
    const float* __restrict__ value, float* __restrict__ part,
    float* __restrict__ zpart) {
  __shared__ _Float16 At[32 * 64 * 8];     // 32 KB
  __shared__ _Float16 Bt[2][4 * 256 * 8];  // 2 x 16 KB
  __shared__ float wbuf[64];

  const int tid = threadIdx.x;
  const int lane = tid & 63;
  const int wid = tid >> 6;  // 0..7
  const int wr = wid >> 2;   // 0..1 (row half)
  const int wc = wid & 3;    // 0..3 (u quarter)
  const int lx = lane & 15;
  const int lg = lane >> 4;
  const int row0 = blockIdx.x * 64;
  const int b = blockIdx.x >> 4;
  const int ch = blockIdx.x & 15;

  // ---- A-stage: batch 8 row-loads (1 KB contiguous per wave-load) ----
  float4 areg[8];
#pragma unroll
  for (int i = 0; i < 8; ++i) {
    const int r = wid * 8 + i;
    areg[i] = *reinterpret_cast<const float4*>(key + (size_t)(row0 + r) * UD +
                                               lane * 4);
  }
  // ---- B phase-0 loads (linear 16 KB) ----
  f16x8 b0a = reinterpret_cast<const f16x8*>(wq16t)[tid];
  f16x8 b0b = reinterpret_cast<const f16x8*>(wq16t)[tid + 512];

  // ---- A cvt + swizzled LDS write ----
  {
    const int ks = lane >> 1;  // 0..31
    const int jh = lane & 1;   // 16-B half
#pragma unroll
    for (int i = 0; i < 8; ++i) {
      const int r = wid * 8 + i;
      f16x4 h;
      h[0] = (_Float16)areg[i].x; h[1] = (_Float16)areg[i].y;
      h[2] = (_Float16)areg[i].z; h[3] = (_Float16)areg[i].w;
      const int rs = r ^ (ks & 7);
      *reinterpret_cast<f16x4*>(At + ((ks * 64 + rs) * 8 + jh * 4)) = h;
    }
  }
  reinterpret_cast<f16x8*>(Bt[0])[tid] = b0a;
  reinterpret_cast<f16x8*>(Bt[0])[tid + 512] = b0b;
  __syncthreads();

  f32x4 acc[2][4];
#pragma unroll
  for (int m = 0; m < 2; ++m)
#pragma unroll
    for (int n = 0; n < 4; ++n) acc[m][n] = (f32x4){0.f, 0.f, 0.f, 0.f};

#pragma unroll
  for (int p = 0; p < 8; ++p) {
    const int cur = p & 1;
    f16x8 breg0, breg1;
    if (p < 7) {  // T14: issue next-phase loads now, commit after MFMA
      const f16x8* src =
          reinterpret_cast<const f16x8*>(wq16t + (size_t)(p + 1) * 8192);
      breg0 = src[tid];
      breg1 = src[tid + 512];
    }
    const int ksg = p * 4 + lg;
    f16x8 af[2], bf[4];
#pragma unroll
    for (int m = 0; m < 2; ++m) {
      const int row = wr * 32 + m * 16 + lx;
      const int rs = row ^ (ksg & 7);
      af[m] = *reinterpret_cast<const f16x8*>(At + (ksg * 64 + rs) * 8);
    }
#pragma unroll
    for (int n = 0; n < 4; ++n) {
      const int u = wc * 64 + n * 16 + lx;
      bf[n] = *reinterpret_cast<const f16x8*>(Bt[cur] + (lg * 256 + u) * 8);
    }
#pragma unroll
    for (int m = 0; m < 2; ++m)
#pragma unroll
      for (int n = 0; n < 4; ++n)
        acc[m][n] = __builtin_amdgcn_mfma_f32_16x16x32_f16(af[m], bf[n],
                                                           acc[m][n], 0, 0, 0);
    if (p < 7) {
      reinterpret_cast<f16x8*>(Bt[cur ^ 1])[tid] = breg0;
      reinterpret_cast<f16x8*>(Bt[cur ^ 1])[tid + 512] = breg1;
    }
    __syncthreads();
  }

  // ---- epilogue: tanh, dot v, shfl-reduce over lx, LDS-reduce over wc ----
  float vv[4];
#pragma unroll
  for (int n = 0; n < 4; ++n) vv[n] = v[wc * 64 + n * 16 + lx];

  float* red = (float*)At;  // At free after final barrier
  float prt[2][4];
#pragma unroll
  for (int m = 0; m < 2; ++m)
#pragma unroll
    for (int r = 0; r < 4; ++r) prt[m][r] = 0.f;
#pragma unroll
  for (int m = 0; m < 2; ++m)
#pragma unroll
    for (int n = 0; n < 4; ++n)
#pragma unroll
      for (int r = 0; r < 4; ++r)
        prt[m][r] += vv[n] * fast_tanh(acc[m][n][r]);

#pragma unroll
  for (int m = 0; m < 2; ++m)
#pragma unroll
    for (int r = 0; r < 4; ++r) {
      float s = prt[m][r];
      s += __shfl_xor(s, 1);
      s += __shfl_xor(s, 2);
      s += __shfl_xor(s, 4);
      s += __shfl_xor(s, 8);
      if (lx == 0) red[(wr * 32 + m * 16 + lg * 4 + r) * 4 + wc] = s;
    }
  __syncthreads();

  // ---- e = exp (unnormalized), z partial ----
  const int vl = vlen[b];
  if (tid < 64) {
    const float sval =
        red[tid * 4 + 0] + red[tid * 4 + 1] + red[tid * 4 + 2] + red[tid * 4 + 3];
    const int kglob = ch * 64 + tid;
    const float e = (vl == 0) ? 1.0f : ((kglob < vl) ? __expf(sval) : 0.0f);
    wbuf[tid] = e;
    float zz = e;
    zz += __shfl_xor(zz, 1);
    zz += __shfl_xor(zz, 2);
    zz += __shfl_xor(zz, 4);
    zz += __shfl_xor(zz, 8);
    zz += __shfl_xor(zz, 16);
    zz += __shfl_xor(zz, 32);
    if (tid == 0) zpart[b * 16 + ch] = zz;
  }
  __syncthreads();

  // ---- PV partial: half = tid>>8 covers 32 k-rows; d = tid&255 ----
  const int half = tid >> 8;
  const int d = tid & 255;
  const float* vb =
      value + ((size_t)b * TK + ch * 64 + half * 32) * UD + d;
  float a = 0.f;
#pragma unroll 8
  for (int k = 0; k < 32; ++k)
    a = fmaf(wbuf[half * 32 + k], vb[(size_t)k * UD], a);
  float* racc = (float*)Bt;  // 512 floats, free after MFMA phases
  racc[half * 256 + d] = a;
  __syncthreads();
  if (tid < 256)
    part[(size_t)(b * 16 + ch) * UD + tid] = racc[tid] + racc[256 + tid];
}

// ---------------------------------------------------------------------------
// K2: out[b,q,d] = (sum_c part[b,c,d]) / (sum_c zpart[b,c]), broadcast over
// 64 q-rows per block. 512 blocks x 256 thr.
// ---------------------------------------------------------------------------
__global__ __launch_bounds__(256) void bcast_kernel(
    const float* __restrict__ part, const float* __restrict__ zpart,
    float* __restrict__ out) {
  const int b = blockIdx.x >> 4;
  const int qc = blockIdx.x & 15;
  const int tid = threadIdx.x;
  const int qoff = tid >> 6;      // 0..3
  const int dd = (tid & 63) * 4;  // 0..252

  float Z = 0.f;
#pragma unroll
  for (int c = 0; c < 16; ++c) Z += zpart[b * 16 + c];
  const float rz = 1.0f / Z;

  float4 s = make_float4(0.f, 0.f, 0.f, 0.f);
#pragma unroll
  for (int c = 0; c < 16; ++c) {
    const float4 p = *reinterpret_cast<const float4*>(
        &part[(size_t)(b * 16 + c) * UD + dd]);
    s.x += p.x; s.y += p.y; s.z += p.z; s.w += p.w;
  }
  s.x *= rz; s.y *= rz; s.z *= rz; s.w *= rz;

  float* ob = out + (size_t)b * TQ * UD + (size_t)qc * 64 * UD;
#pragma unroll 4
  for (int q4 = 0; q4 < 16; ++q4) {
    *reinterpret_cast<float4*>(&ob[(size_t)(q4 * 4 + qoff) * UD + dd]) = s;
  }
}

// ---------------------------------------------------------------------------
extern "C" void kernel_launch(void* const* d_in, const int* in_sizes, int n_in,
                              void* d_out, int out_size, void* d_ws,
                              size_t ws_size, hipStream_t stream) {
  // inputs: 0 query, 1 key, 2 value, 3 valid_length, 4 W_k, 5 W_q, 6 v
  const float* key = (const float*)d_in[1];
  const float* value = (const float*)d_in[2];
  const int* vlen = (const int*)d_in[3];
  const float* Wq = (const float*)d_in[5];
  const float* v = (const float*)d_in[6];
  float* out = (float*)d_out;

  char* ws = (char*)d_ws;
  _Float16* wq16t = (_Float16*)(ws);     // 128 KB (k-slot-major f16 Wq)
  float* part = (float*)(ws + 131072);   // 512 KB
  float* zpart = (float*)(ws + 655360);  // 2 KB

  cvt_wq_kernel<<<32, 256, 0, stream>>>(Wq, wq16t);
  fused_kernel<<<NB * 16, 512, 0, stream>>>(key, wq16t, v, vlen, value, part,
                                            zpart);
  bcast_kernel<<<NB * 16, 256, 0, stream>>>(part, zpart, out);
}